// Round 9
// baseline (180.357 us; speedup 1.0000x reference)
//
#include <hip/hip_runtime.h>
#include <hip/hip_fp16.h>

// KnnExpansion: out[f, n] = sum_k alpha[i[n,k], f] * exp(-0.5 * d[n,k] / sigma^2)
// N=131072, K=32, M=65536, F=64.
//
// Proven structure (r7/r8): fused in-register quartile partition + 4-phase
// L2-resident gather. This round:
//  (1) prologue stream loads hoisted to raw[8] (MLP=8, latency paid once)
//  (2) dword gathers: 2 f16 channels/lane, 32 lanes/row, one wave-instr
//      gathers TWO query-rows (lane half selects s0/s1) -> VMEM gather
//      instruction count halved, outstanding-slots per element halved.
// Epilogue: shfl_xor(32) cross-half reduce, LDS-transposed [F,N] store.

#define N_Q    131072
#define K_NB   32
#define F_CH   64
#define M_ROWS 65536

// ---- pre-pass: alpha f32 -> f16 (streaming, ~3us) ----
__global__ __launch_bounds__(256) void cvt_alpha_f16(
    const float* __restrict__ alpha, __half* __restrict__ a16)
{
    const int t = blockIdx.x * 256 + threadIdx.x;
    const float4 v0 = ((const float4*)alpha)[(size_t)t * 2 + 0];
    const float4 v1 = ((const float4*)alpha)[(size_t)t * 2 + 1];
    union { __half2 h2[4]; uint4 u; } pk;
    pk.h2[0] = __floats2half2_rn(v0.x, v0.y);
    pk.h2[1] = __floats2half2_rn(v0.z, v0.w);
    pk.h2[2] = __floats2half2_rn(v1.x, v1.y);
    pk.h2[3] = __floats2half2_rn(v1.z, v1.w);
    ((uint4*)a16)[t] = pk.u;
}

// ---- fused main ----
__global__ __launch_bounds__(512) void knn_exp_fused2(
    const float*  __restrict__ dmat,   // [N, 32]
    const int*    __restrict__ imat,   // [N, 32]
    const __half* __restrict__ a16,    // [65536, 64]
    const float*  __restrict__ sigma,  // [1]
    float*        __restrict__ out)    // [64, N]
{
    __shared__ float    tile[64][65];        // +1 pad
    __shared__ unsigned sortbuf[8][8][32];   // wave-local sort scratch

    const int lane = threadIdx.x & 63;
    const int wave = threadIdx.x >> 6;       // 8 waves x 8 queries
    const int n0   = blockIdx.x * 64;
    const bool hi  = (lane >= 32);
    const unsigned lanebyte4 = (unsigned)(lane & 31) * 4u;

    const float s = sigma[0];
    const float c = -0.5f / (s * s);

    // ---- hoisted stream loads: lo lanes -> d, hi lanes -> i (2x128B segs)
    const int nbase = n0 + wave * 8;
    const char* pbase = hi
        ? (const char*)&imat[(size_t)nbase * K_NB + (lane - 32)]
        : (const char*)&dmat[(size_t)nbase * K_NB + lane];
    unsigned raw[8];
    #pragma unroll
    for (int qi = 0; qi < 8; ++qi)
        raw[qi] = __builtin_nontemporal_load(
            (const unsigned*)(pbase + (size_t)qi * (K_NB * 4)));

    __builtin_amdgcn_sched_barrier(0);   // keep the 8 loads issued as a batch

    // ---- in-register quartile partition, pack (idx<<16 | f16(w)) ----
    #pragma unroll
    for (int qi = 0; qi < 8; ++qi) {
        const float wv = __expf(c * __uint_as_float(raw[qi])); // valid on lo
        const int   iv = (int)raw[qi];                         // valid on hi

        const unsigned hbits = (unsigned)__half_as_ushort(__float2half_rn(wv));
        const unsigned hb    = (unsigned)__shfl((int)hbits, lane & 31);

        const int quart = (iv >> 14) & 3;
        const unsigned long long m0 = __ballot(hi && quart == 0);
        const unsigned long long m1 = __ballot(hi && quart == 1);
        const unsigned long long m2 = __ballot(hi && quart == 2);
        const unsigned long long m3 = __ballot(hi && quart == 3);
        const int b1 = __popcll(m0);
        const int b2 = b1 + __popcll(m1);
        const int b3 = b2 + __popcll(m2);
        const unsigned long long mq =
            (quart == 0) ? m0 : (quart == 1) ? m1 : (quart == 2) ? m2 : m3;
        const int bq =
            (quart == 0) ? 0 : (quart == 1) ? b1 : (quart == 2) ? b2 : b3;
        const unsigned long long below = (1ull << lane) - 1ull;
        const int pos = bq + __popcll(mq & below);

        if (hi)
            sortbuf[wave][qi][pos] = ((unsigned)iv << 16) | (hb & 0xFFFFu);
    }

    // wave-local RAW through LDS (lgkmcnt-ordered, no barrier needed)
    unsigned pv[8];
    float accL[8], accH[8];
    #pragma unroll
    for (int qi = 0; qi < 8; ++qi) {
        pv[qi]  = sortbuf[wave][qi][lane & 31];
        accL[qi] = 0.0f;
        accH[qi] = 0.0f;
    }

    // ---- 4-phase gather: phase p ~= quartile p (2 MiB L2-resident slice).
    // One dword wave-instr gathers TWO rows: lo half -> entry j (s0),
    // hi half -> entry j+1 (s1); each lane covers channels 2c, 2c+1.
    #pragma unroll
    for (int p = 0; p < 4; ++p) {
        #pragma unroll
        for (int qi = 0; qi < 8; ++qi) {
            #pragma unroll
            for (int j = 0; j < 8; j += 2) {
                const unsigned s0 = (unsigned)__builtin_amdgcn_readlane(
                    (int)pv[qi], p * 8 + j);
                const unsigned s1 = (unsigned)__builtin_amdgcn_readlane(
                    (int)pv[qi], p * 8 + j + 1);

                const unsigned rowoff = hi ? (s1 >> 16) : (s0 >> 16);
                const unsigned off = rowoff * 128u + lanebyte4;
                const unsigned u = *(const unsigned*)((const char*)a16 + off);

                __half_raw hw;
                hw.x = (unsigned short)((hi ? s1 : s0) & 0xFFFFu);
                const float w = __half2float(__half(hw));

                union { unsigned u32; __half2 h2; } cv;
                cv.u32 = u;
                const float2 f2 = __half22float2(cv.h2);
                accL[qi] = fmaf(w, f2.x, accL[qi]);
                accH[qi] = fmaf(w, f2.y, accH[qi]);
            }
        }
    }

    // ---- cross-half reduce + transpose tile write (lo half writes) ----
    #pragma unroll
    for (int qi = 0; qi < 8; ++qi) {
        const float sL = accL[qi] + __shfl_xor(accL[qi], 32);
        const float sH = accH[qi] + __shfl_xor(accH[qi], 32);
        if (!hi) {
            tile[wave * 8 + qi][2 * lane]     = sL;
            tile[wave * 8 + qi][2 * lane + 1] = sH;
        }
    }

    __syncthreads();

    // coalesced [F, N] store: each wave writes 8 channel-rows of 64 floats
    #pragma unroll
    for (int fi = 0; fi < 8; ++fi) {
        const int f = wave * 8 + fi;
        __builtin_nontemporal_store(tile[lane][f],
                                    &out[(size_t)f * N_Q + n0 + lane]);
    }
}

// ---- fallback: pure fp32 (no workspace) ----
__global__ __launch_bounds__(256) void knn_exp_f32(
    const float* __restrict__ dmat,
    const int*   __restrict__ imat,
    const float* __restrict__ alpha,
    const float* __restrict__ sigma,
    float*       __restrict__ out)
{
    __shared__ float tile[64][65];
    const int lane = threadIdx.x & 63;
    const int wave = threadIdx.x >> 6;
    const int n0   = blockIdx.x * 64;
    const float s = sigma[0];
    const float c = -0.5f / (s * s);

    for (int qi = 0; qi < 16; ++qi) {
        const int q = wave * 16 + qi;
        const int n = n0 + q;
        float wv = 0.0f;
        int   iv = 0;
        if (lane < 32) {
            wv = __expf(c * dmat[(size_t)n * K_NB + lane]);
        } else {
            iv = imat[(size_t)n * K_NB + (lane - 32)];
        }
        float acc = 0.0f;
        #pragma unroll
        for (int k = 0; k < K_NB; ++k) {
            const float wk = __int_as_float(
                __builtin_amdgcn_readlane(__float_as_int(wv), k));
            const int   ik = __builtin_amdgcn_readlane(iv, 32 + k);
            acc = fmaf(wk, alpha[(size_t)ik * F_CH + lane], acc);
        }
        tile[q][lane] = acc;
    }
    __syncthreads();
    #pragma unroll
    for (int fi = 0; fi < 16; ++fi) {
        const int f = wave * 16 + fi;
        out[(size_t)f * N_Q + n0 + lane] = tile[lane][f];
    }
}

extern "C" void kernel_launch(void* const* d_in, const int* in_sizes, int n_in,
                              void* d_out, int out_size, void* d_ws, size_t ws_size,
                              hipStream_t stream) {
    const float* dmat  = (const float*)d_in[0];
    const int*   imat  = (const int*)d_in[1];
    const float* alpha = (const float*)d_in[2];
    const float* sigma = (const float*)d_in[3];
    float* out = (float*)d_out;

    const size_t bytes_a16 = (size_t)M_ROWS * F_CH * sizeof(__half);  // 8 MiB

    if (ws_size >= bytes_a16) {
        __half* a16 = (__half*)d_ws;
        hipLaunchKernelGGL(cvt_alpha_f16, dim3(M_ROWS * F_CH / 8 / 256),
                           dim3(256), 0, stream, alpha, a16);
        hipLaunchKernelGGL(knn_exp_fused2, dim3(N_Q / 64), dim3(512), 0,
                           stream, dmat, imat, a16, sigma, out);
    } else {
        hipLaunchKernelGGL(knn_exp_f32, dim3(N_Q / 64), dim3(256), 0, stream,
                           dmat, imat, alpha, sigma, out);
    }
}

// Round 10
// 61.726 us; speedup vs baseline: 2.9219x; 2.9219x over previous
//
#include <hip/hip_runtime.h>
#include <hip/hip_fp16.h>

// KnnExpansion: out[f, n] = sum_k alpha[i[n,k], f] * exp(-0.5 * d[n,k] / sigma^2)
// N=131072, K=32, M=65536, F=64.
//
// Proven structure (r7/r8): fused in-register quartile partition + 4-phase
// L2-resident gather (ushort per-lane gather, SGPR base via readlane,
// VGPR=32, occupancy ~71%). Round 9's dword-gather variant exploded VGPR
// (divergent address selects) -> reverted. This round keeps r8 byte-for-byte
// in the gather loop and ONLY hoists the 8 prologue stream loads into a
// batched raw[8] issue (MLP=8, cold-HBM latency paid once instead of 8x).

#define N_Q    131072
#define K_NB   32
#define F_CH   64
#define M_ROWS 65536

// ---- pre-pass: alpha f32 -> f16 (streaming, ~3us) ----
__global__ __launch_bounds__(256) void cvt_alpha_f16(
    const float* __restrict__ alpha, __half* __restrict__ a16)
{
    const int t = blockIdx.x * 256 + threadIdx.x;
    const float4 v0 = ((const float4*)alpha)[(size_t)t * 2 + 0];
    const float4 v1 = ((const float4*)alpha)[(size_t)t * 2 + 1];
    union { __half2 h2[4]; uint4 u; } pk;
    pk.h2[0] = __floats2half2_rn(v0.x, v0.y);
    pk.h2[1] = __floats2half2_rn(v0.z, v0.w);
    pk.h2[2] = __floats2half2_rn(v1.x, v1.y);
    pk.h2[3] = __floats2half2_rn(v1.z, v1.w);
    ((uint4*)a16)[t] = pk.u;
}

// ---- fused main: batched prologue + in-register quartile partition +
//      4-phase L2-resident gather (r8-proven consume loop) ----
__global__ __launch_bounds__(512) void knn_exp_fused3(
    const float*  __restrict__ dmat,   // [N, 32]
    const int*    __restrict__ imat,   // [N, 32]
    const __half* __restrict__ a16,    // [65536, 64]
    const float*  __restrict__ sigma,  // [1]
    float*        __restrict__ out)    // [64, N]
{
    __shared__ float    tile[64][65];        // +1 pad
    __shared__ unsigned sortbuf[8][8][32];   // wave-local sort scratch

    const int lane = threadIdx.x & 63;
    const int wave = threadIdx.x >> 6;       // 8 waves x 8 queries
    const int n0   = blockIdx.x * 64;
    const bool hi  = (lane >= 32);
    const unsigned lane2 = (unsigned)lane * 2;

    const float s = sigma[0];
    const float c = -0.5f / (s * s);

    // ---- batched prologue: 8 stream loads issued back-to-back ----
    // lo lanes -> d[n][lane], hi lanes -> i[n][lane-32]; one dword/lane
    // covers a full query row pair (2 x 128B coalesced segments per load).
    const int nbase = n0 + wave * 8;
    const char* pbase = hi
        ? (const char*)&imat[(size_t)nbase * K_NB + (lane - 32)]
        : (const char*)&dmat[(size_t)nbase * K_NB + lane];
    unsigned raw[8];
    #pragma unroll
    for (int qi = 0; qi < 8; ++qi)
        raw[qi] = __builtin_nontemporal_load(
            (const unsigned*)(pbase + (size_t)qi * (K_NB * 4)));

    __builtin_amdgcn_sched_barrier(0);   // keep the batch; no sinking

    // ---- in-register quartile partition, pack (idx<<16 | f16(w)) ----
    #pragma unroll
    for (int qi = 0; qi < 8; ++qi) {
        const float wv = __expf(c * __uint_as_float(raw[qi])); // valid on lo
        const int   iv = (int)raw[qi];                         // valid on hi

        const unsigned hbits = (unsigned)__half_as_ushort(__float2half_rn(wv));
        const unsigned hb    = (unsigned)__shfl((int)hbits, lane & 31);

        const int quart = (iv >> 14) & 3;
        const unsigned long long m0 = __ballot(hi && quart == 0);
        const unsigned long long m1 = __ballot(hi && quart == 1);
        const unsigned long long m2 = __ballot(hi && quart == 2);
        const unsigned long long m3 = __ballot(hi && quart == 3);
        const int b1 = __popcll(m0);
        const int b2 = b1 + __popcll(m1);
        const int b3 = b2 + __popcll(m2);
        const unsigned long long mq =
            (quart == 0) ? m0 : (quart == 1) ? m1 : (quart == 2) ? m2 : m3;
        const int bq =
            (quart == 0) ? 0 : (quart == 1) ? b1 : (quart == 2) ? b2 : b3;
        const unsigned long long below = (1ull << lane) - 1ull;
        const int pos = bq + __popcll(mq & below);

        if (hi)
            sortbuf[wave][qi][pos] = ((unsigned)iv << 16) | (hb & 0xFFFFu);
    }

    // wave-local RAW through LDS (lgkmcnt-ordered, no barrier needed)
    unsigned pv[8];
    float    acc[8];
    #pragma unroll
    for (int qi = 0; qi < 8; ++qi) {
        pv[qi]  = sortbuf[wave][qi][lane & 31];
        acc[qi] = 0.0f;
    }

    // ---- r8-proven consume: phase p ~= quartile p (2 MiB L2 slice) ----
    #pragma unroll
    for (int p = 0; p < 4; ++p) {
        #pragma unroll
        for (int qi = 0; qi < 8; ++qi) {
            #pragma unroll
            for (int j = 0; j < 8; ++j) {
                const unsigned pk = (unsigned)__builtin_amdgcn_readlane(
                    (int)pv[qi], p * 8 + j);              // SGPR
                __half_raw hr; hr.x = (unsigned short)(pk & 0xFFFFu);
                const float w = __half2float(__half(hr));
                const unsigned off = ((pk >> 16) << 7) + lane2;
                const __half av = *(const __half*)((const char*)a16 + off);
                acc[qi] = fmaf(w, __half2float(av), acc[qi]);
            }
        }
    }

    #pragma unroll
    for (int qi = 0; qi < 8; ++qi)
        tile[wave * 8 + qi][lane] = acc[qi];

    __syncthreads();

    // coalesced [F, N] store: each wave writes 8 channel-rows of 64 floats
    #pragma unroll
    for (int fi = 0; fi < 8; ++fi) {
        const int f = wave * 8 + fi;
        __builtin_nontemporal_store(tile[lane][f],
                                    &out[(size_t)f * N_Q + n0 + lane]);
    }
}

// ---- fallback: pure fp32 (no workspace) ----
__global__ __launch_bounds__(256) void knn_exp_f32(
    const float* __restrict__ dmat,
    const int*   __restrict__ imat,
    const float* __restrict__ alpha,
    const float* __restrict__ sigma,
    float*       __restrict__ out)
{
    __shared__ float tile[64][65];
    const int lane = threadIdx.x & 63;
    const int wave = threadIdx.x >> 6;
    const int n0   = blockIdx.x * 64;
    const float s = sigma[0];
    const float c = -0.5f / (s * s);

    for (int qi = 0; qi < 16; ++qi) {
        const int q = wave * 16 + qi;
        const int n = n0 + q;
        float wv = 0.0f;
        int   iv = 0;
        if (lane < 32) {
            wv = __expf(c * dmat[(size_t)n * K_NB + lane]);
        } else {
            iv = imat[(size_t)n * K_NB + (lane - 32)];
        }
        float acc = 0.0f;
        #pragma unroll
        for (int k = 0; k < K_NB; ++k) {
            const float wk = __int_as_float(
                __builtin_amdgcn_readlane(__float_as_int(wv), k));
            const int   ik = __builtin_amdgcn_readlane(iv, 32 + k);
            acc = fmaf(wk, alpha[(size_t)ik * F_CH + lane], acc);
        }
        tile[q][lane] = acc;
    }
    __syncthreads();
    #pragma unroll
    for (int fi = 0; fi < 16; ++fi) {
        const int f = wave * 16 + fi;
        out[(size_t)f * N_Q + n0 + lane] = tile[lane][f];
    }
}

extern "C" void kernel_launch(void* const* d_in, const int* in_sizes, int n_in,
                              void* d_out, int out_size, void* d_ws, size_t ws_size,
                              hipStream_t stream) {
    const float* dmat  = (const float*)d_in[0];
    const int*   imat  = (const int*)d_in[1];
    const float* alpha = (const float*)d_in[2];
    const float* sigma = (const float*)d_in[3];
    float* out = (float*)d_out;

    const size_t bytes_a16 = (size_t)M_ROWS * F_CH * sizeof(__half);  // 8 MiB

    if (ws_size >= bytes_a16) {
        __half* a16 = (__half*)d_ws;
        hipLaunchKernelGGL(cvt_alpha_f16, dim3(M_ROWS * F_CH / 8 / 256),
                           dim3(256), 0, stream, alpha, a16);
        hipLaunchKernelGGL(knn_exp_fused3, dim3(N_Q / 64), dim3(512), 0,
                           stream, dmat, imat, a16, sigma, out);
    } else {
        hipLaunchKernelGGL(knn_exp_f32, dim3(N_Q / 64), dim3(256), 0, stream,
                           dmat, imat, alpha, sigma, out);
    }
}